// Round 4
// baseline (246.395 us; speedup 1.0000x reference)
//
#include <hip/hip_runtime.h>
#include <hip/hip_bf16.h>

typedef unsigned short ushort_t;
typedef __bf16 bf16x8 __attribute__((ext_vector_type(8)));
typedef unsigned short us8 __attribute__((ext_vector_type(8)));
typedef float f32x4 __attribute__((ext_vector_type(4)));

#define NPAD 8704
#define SENT (1 << 20)

__device__ __forceinline__ ushort_t f2b(float f) {
    union { float f; unsigned int u; } v; v.f = f;
    unsigned int u = v.u;
    unsigned int r = (u + 0x7FFFu + ((u >> 16) & 1u)) >> 16;
    return (ushort_t)r;
}
__device__ __forceinline__ float sigmoidf_(float x) {
    return 1.f / (1.f + __expf(-x));
}

__global__ void fill_kernel(float* out, long long n, float val) {
    long long i = (long long)blockIdx.x * blockDim.x + threadIdx.x;
    if (i < n) out[i] = val;
}

// ---------------------------------------------------------------------------
// Packed B layout for mfma_f32_16x16x32_bf16 (per 64-col block c, 32-k group
// kk): 4 col-subtiles su, 64 lanes (lane = k-oct*16 + col&15), 8 bf16.
// Packed A layout: tile (mt = pos/16, kk): 16 rows x 32 k; lane l holds
// row = l&15, k-oct = l>>4, 8 contiguous bf16. 1 KB/wave contiguous loads.
// ---------------------------------------------------------------------------
#define PACKSZ(O, K) ((long long)((O) >= 64 ? (O) >> 6 : 1) * ((K) >> 5) * 2048)

// ---------------------------------------------------------------------------
// Ballot-based sort with 64-PADDED segments: each agent's segment is padded
// to a multiple of 64; dummy positions get perm = SENT (gather clamps to row
// 0, scatters skip). All ttab tiles are full & 64-aligned -> packed-A safe.
// ---------------------------------------------------------------------------
__global__ void sort_kernel(const int* __restrict__ ids, int N,
                            int* __restrict__ perm, int* __restrict__ seg,
                            int4* __restrict__ ttab, int* __restrict__ tcount) {
    __shared__ int hist[16][8];
    __shared__ int wbase[16][8];
    __shared__ int atot[8];
    __shared__ int abase[8];
    int tid = threadIdx.x, wave = tid >> 6, lane = tid & 63;
    int base = wave * 512;
    unsigned long long lt = (lane == 63) ? 0x7fffffffffffffffull
                                         : ((1ull << lane) - 1ull);
    int myid[8], rank[8];
    int run[8] = {0, 0, 0, 0, 0, 0, 0, 0};
    #pragma unroll
    for (int i = 0; i < 8; i++) myid[i] = ids[base + i * 64 + lane] & 7;
    #pragma unroll
    for (int i = 0; i < 8; i++) {
        int a = myid[i];
        int r = 0;
        #pragma unroll
        for (int a2 = 0; a2 < 8; a2++) {
            unsigned long long m = __ballot(a == a2);
            if (a2 == a) r = run[a2] + __popcll(m & lt);
            run[a2] += __popcll(m);
        }
        rank[i] = r;
    }
    if (lane == 0) {
        #pragma unroll
        for (int a = 0; a < 8; a++) hist[wave][a] = run[a];
    }
    __syncthreads();
    if (tid < 8) {
        int a = tid, s = 0;
        for (int w = 0; w < 16; w++) { wbase[w][a] = s; s += hist[w][a]; }
        atot[a] = s;
    }
    __syncthreads();
    if (tid == 0) {
        int s = 0;
        for (int a = 0; a < 8; a++) {
            abase[a] = s; seg[a] = s;
            s += (atot[a] + 63) & ~63;      // padded segment
        }
        seg[8] = s;
        int T = 0;
        for (int a = 0; a < 8; a++) {
            int e = abase[a] + atot[a];
            int pe = abase[a] + ((atot[a] + 63) & ~63);
            for (int m = abase[a]; m < pe; m += 64) {
                int z = e < m + 64 ? e : m + 64;
                ttab[T++] = make_int4(a, m, z, 0);
            }
        }
        *tcount = T;
    }
    __syncthreads();
    #pragma unroll
    for (int i = 0; i < 8; i++) {
        int a = myid[i];
        perm[abase[a] + wbase[wave][a] + rank[i]] = base + i * 64 + lane;
    }
    // sentinel-fill dummy pad slots + buffer tail
    for (int a = 0; a < 8; a++) {
        int e = abase[a] + atot[a];
        int pe = abase[a] + ((atot[a] + 63) & ~63);
        for (int p2 = e + tid; p2 < pe; p2 += 1024) perm[p2] = SENT;
    }
    int Pend = abase[7] + ((atot[7] + 63) & ~63);
    for (int p2 = Pend + tid; p2 < NPAD; p2 += 1024) perm[p2] = SENT;
}

// ---------------------------------------------------------------------------
// Fused prep: masked weights -> packed-B bf16; activations gathered to
// packed-A pos-order bf16; GRU weights -> packed-B bf16.
// ---------------------------------------------------------------------------
__device__ __forceinline__ void maskw_item(const float* __restrict__ alpha,
                                           const float* __restrict__ w,
                                           ushort_t* __restrict__ wm,
                                           long long idx, int O, int G, int dup) {
    int g = (int)(idx % G);
    long long t2 = idx / G;
    int o = (int)(t2 % O);
    int a = (int)(t2 / O);
    const float* al = alpha + idx * 6;
    float p[6];
    float mx = -1e30f;
    #pragma unroll
    for (int i = 0; i < 6; i++) { p[i] = al[i] * 0.2f; mx = fmaxf(mx, p[i]); }
    float s = 0.f;
    #pragma unroll
    for (int i = 0; i < 6; i++) { p[i] = __expf(p[i] - mx); s += p[i]; }
    float inv = 1.f / s;
    #pragma unroll
    for (int i = 0; i < 6; i++) p[i] *= inv;
    float mk[4] = { p[0] + p[1] + p[2], p[0] + p[3] + p[4],
                    p[1] + p[3] + p[5], p[2] + p[4] + p[5] };
    int K = G * 4;
    const float* wr = w + (long long)o * K + g * 4;
    ushort_t* base = wm + (long long)a * PACKSZ(O, K);
    int k0 = g * 4;
    int c = o >> 6, su = (o >> 4) & 3, n = o & 15;
    int kk = k0 >> 5, q = (k0 >> 3) & 3, e0 = k0 & 7;
    long long off = (((long long)(c * (K >> 5) + kk) * 4 + su) * 64 + (q * 16 + n)) * 8 + e0;
    #pragma unroll
    for (int t = 0; t < 4; t++) {
        ushort_t v = f2b(wr[t] * mk[t]);
        base[off + t] = v;
        if (dup) {
            base[off + t + 512] = v;
            base[off + t + 1024] = v;
            base[off + t + 1536] = v;
        }
    }
}

// gather fp32 rows (via perm) into packed-A bf16. i indexes us8 slots:
// i = (mt*KK + kk)*64 + lane.
__device__ __forceinline__ void canon_gather_packed(const float* __restrict__ src,
                                                    ushort_t* __restrict__ dst,
                                                    const int* __restrict__ perm,
                                                    int ld, long long i) {
    int l = (int)(i & 63);
    int tt = (int)(i >> 6);
    int KK = ld >> 5;
    int mt = tt / KK, kk = tt - mt * KK;
    int row = perm[mt * 16 + (l & 15)];
    if (row >= 8192) row = 0;
    const float* s = src + (long long)row * ld + kk * 32 + (l >> 4) * 8;
    us8 v;
    #pragma unroll
    for (int e = 0; e < 8; e++) v[e] = f2b(s[e]);
    *(us8*)(dst + i * 8) = v;
}

__device__ __forceinline__ void canon_pack_item(const float* __restrict__ src,
                                                ushort_t* __restrict__ dst,
                                                long long i) {
    long long base = i * 8;
    int o_full = (int)(base >> 9);
    int k0 = (int)(base & 511);
    int g = o_full >> 9, o = o_full & 511;
    int c = o >> 6, su = (o >> 4) & 3, n = o & 15;
    int kk = k0 >> 5, q = (k0 >> 3) & 3;
    long long off = (long long)g * 262144 +
        (((long long)(c * 16 + kk) * 4 + su) * 64 + (q * 16 + n)) * 8;
    us8 v;
    #pragma unroll
    for (int e = 0; e < 8; e++) v[e] = f2b(src[base + e]);
    *(us8*)(dst + off) = v;
}

#define PB0 256
#define PB1 2048
#define PB2 2048
#define PB3 64
#define PB4 272
#define PB5 2176
#define PB6 384
#define PB7 384
#define PREP_BLOCKS (PB0+PB1+PB2+PB3+PB4+PB5+PB6+PB7)

__global__ void prep_kernel(const float* fc1_al, const float* fc1_w, ushort_t* wm1,
                            const float* fc2_al, const float* fc2_w, ushort_t* wm2,
                            const float* fc3_al, const float* fc3_w, ushort_t* wm3,
                            const float* fc4_al, const float* fc4_w, ushort_t* wm4,
                            const float* inputs, ushort_t* inp_pos,
                            const float* hidden, ushort_t* hid_pos,
                            const float* wih, ushort_t* wihp,
                            const float* whh, ushort_t* whhp,
                            const int* perm) {
    int b = blockIdx.x;
    int tid = threadIdx.x;
    if (b < PB0) { maskw_item(fc1_al, fc1_w, wm1, (long long)b * 256 + tid, 512, 16, 0); return; }
    b -= PB0;
    if (b < PB1) { maskw_item(fc2_al, fc2_w, wm2, (long long)b * 256 + tid, 512, 128, 0); return; }
    b -= PB1;
    if (b < PB2) { maskw_item(fc3_al, fc3_w, wm3, (long long)b * 256 + tid, 512, 128, 0); return; }
    b -= PB2;
    if (b < PB3) { maskw_item(fc4_al, fc4_w, wm4, (long long)b * 256 + tid, 16, 128, 1); return; }
    b -= PB3;
    if (b < PB4) { canon_gather_packed(inputs, inp_pos, perm, 64, (long long)b * 256 + tid); return; }
    b -= PB4;
    if (b < PB5) { canon_gather_packed(hidden, hid_pos, perm, 512, (long long)b * 256 + tid); return; }
    b -= PB5;
    if (b < PB6) { canon_pack_item(wih, wihp, (long long)b * 256 + tid); return; }
    b -= PB6;
    canon_pack_item(whh, whhp, (long long)b * 256 + tid);
}

// ---------------------------------------------------------------------------
// GEMM: BOTH A and B pre-packed in MFMA fragment order -> pure global->reg->
// MFMA stream, ZERO barriers / ZERO LDS in the K-loop. Register double-buffer
// (prefetch distance 1); compiler emits counted vmcnt waits. Fragment
// transpose (C-frag -> A-frag) done once per block in an LDS epilogue.
// ---------------------------------------------------------------------------
template <typename OT, int NC, int PACKOUT>
__launch_bounds__(256, 4)
__global__ void gemm_tiled(const ushort_t* __restrict__ Apk, int K,
                           const ushort_t* __restrict__ Wpk, long long wstride,
                           const float* __restrict__ bias,
                           OT* __restrict__ Out, int ldo,
                           const int4* __restrict__ ttab,
                           const int* __restrict__ tcount,
                           const int* __restrict__ perm,
                           int O, int relu) {
    int t = blockIdx.x;
    if (t >= *tcount) return;
    int4 tt = ttab[t];
    int a = tt.x, pos0 = tt.y;
    constexpr int JJ = 2 * NC;

    int tid = threadIdx.x;
    int wave = tid >> 6, lane = tid & 63;
    int wr = (wave >> 1) & 1, wc = wave & 1;
    int quad = lane >> 4, l16 = lane & 15;

    int KK = K >> 5;
    int KKh = KK >> 1;
    int c_idx = blockIdx.y * NC + (NC == 2 ? wc : 0);
    const ushort_t* wb = Wpk + (long long)a * wstride +
        (long long)c_idx * KK * 2048 + lane * 8;
    const ushort_t* ap = Apk + (long long)(pos0 >> 4) * KK * 512 + lane * 8;

    f32x4 acc[2][JJ];
    #pragma unroll
    for (int i = 0; i < 2; i++)
        #pragma unroll
        for (int j = 0; j < JJ; j++) acc[i][j] = (f32x4){0.f, 0.f, 0.f, 0.f};

    bf16x8 aA[2], bA[JJ], aB[2], bB[JJ];

#define GLOADS(AR, BR, kkv) do {                                              \
    _Pragma("unroll") for (int i2 = 0; i2 < 2; i2++)                          \
        AR[i2] = *(const bf16x8*)(ap + ((long long)(wr * 2 + i2) * KK + (kkv)) * 512); \
    _Pragma("unroll") for (int j2 = 0; j2 < JJ; j2++) {                       \
        int su = (NC == 2) ? j2 : wc * 2 + j2;                                \
        BR[j2] = *(const bf16x8*)(wb + ((kkv) * 4 + su) * 512); }             \
} while (0)
#define GMFMAS(AR, BR) do {                                                   \
    _Pragma("unroll") for (int i2 = 0; i2 < 2; i2++)                          \
        _Pragma("unroll") for (int j2 = 0; j2 < JJ; j2++)                     \
            acc[i2][j2] = __builtin_amdgcn_mfma_f32_16x16x32_bf16(            \
                AR[i2], BR[j2], acc[i2][j2], 0, 0, 0);                        \
} while (0)

    GLOADS(aA, bA, 0);
    #pragma unroll 1
    for (int kk2 = 0; kk2 < KKh; kk2++) {
        GLOADS(aB, bB, kk2 * 2 + 1);
        GMFMAS(aA, bA);
        if (kk2 + 1 < KKh) GLOADS(aA, bA, kk2 * 2 + 2);
        GMFMAS(aB, bB);
    }
#undef GLOADS
#undef GMFMAS

    if constexpr (PACKOUT) {
        // C-frag -> packed-A transpose via LDS, then coalesced us8 stores.
        __shared__ ushort_t Cs[64 * 136];
        #pragma unroll
        for (int i = 0; i < 2; i++)
            #pragma unroll
            for (int j = 0; j < JJ; j++) {
                int colL = (NC == 2 ? wc * 64 : wc * 32) + j * 16 + l16;
                int col = blockIdx.y * (64 * NC) + colL;
                float bv = bias[col];
                #pragma unroll
                for (int r = 0; r < 4; r++) {
                    float v = acc[i][j][r] + bv;
                    if (relu) v = fmaxf(v, 0.f);
                    Cs[(wr * 32 + i * 16 + quad * 4 + r) * 136 + colL] = f2b(v);
                }
            }
        __syncthreads();
        int KKo = ldo >> 5;
        int kk0 = blockIdx.y * (2 * NC);
        constexpr int NKK = 2 * NC;
        #pragma unroll
        for (int s2 = 0; s2 < NKK; s2++) {
            int slot = s2 * 256 + tid;
            int l = slot & 63, t4 = slot >> 6;
            int mt = t4 / NKK, kkL = t4 - mt * NKK;
            us8 v = *(const us8*)(&Cs[(mt * 16 + (l & 15)) * 136 + kkL * 32 + (l >> 4) * 8]);
            *(us8*)((ushort_t*)Out + ((long long)((pos0 >> 4) + mt) * KKo + kk0 + kkL) * 512 + l * 8) = v;
        }
    } else {
        // scalar scatter (fc4): guard dummy rows via perm sentinel
        #pragma unroll
        for (int i = 0; i < 2; i++) {
            int mbase = wr * 32 + i * 16 + quad * 4;
            #pragma unroll
            for (int j = 0; j < JJ; j++) {
                int col = (NC == 2 ? wc * 64 : wc * 32) + j * 16 + l16;
                if (col < O) {
                    float bv = bias[col];
                    #pragma unroll
                    for (int r = 0; r < 4; r++) {
                        int pos = pos0 + mbase + r;
                        int orow = perm[pos];
                        if (orow < 8192) {
                            float v = acc[i][j][r] + bv;
                            if (relu) v = fmaxf(v, 0.f);
                            Out[(long long)orow * ldo + col] = v;
                        }
                    }
                }
            }
        }
    }
}

// ---------------------------------------------------------------------------
// Fused GRU: packed-A y1/hid streamed direct from global, packed-B weights
// streamed direct from global. ZERO barriers / ZERO LDS in K-loop. 4 acc
// groups: acc0 = y.wih_r + h.whh_r ; acc1 = y.wih_z + h.whh_z ;
// acc2 = y.wih_n ; acc3 = h.whh_n. Epilogue: gates + scattered fp32 out_h +
// LDS transpose -> packed-A hp for fc2.
// ---------------------------------------------------------------------------
__launch_bounds__(256, 2)
__global__ void gru_fused(const ushort_t* __restrict__ y1,       // packed-A
                          const ushort_t* __restrict__ hid,      // packed-A
                          const float* __restrict__ hidden_f,    // [N,H] orig fp32
                          const ushort_t* __restrict__ wihp,     // packed-B 3x(512,512)
                          const ushort_t* __restrict__ whhp,
                          const float* __restrict__ bih,
                          const float* __restrict__ bhh,
                          const int* __restrict__ perm,
                          float* __restrict__ out_h_f,           // [N,H] orig fp32
                          ushort_t* __restrict__ hp,             // packed-A out
                          const int4* __restrict__ ttab,
                          const int* __restrict__ tcount,
                          int H) {
    int t = blockIdx.x;
    if (t >= *tcount) return;
    int pos0 = ttab[t].y;
    int mt0 = pos0 >> 4;

    int tid = threadIdx.x;
    int wave = tid >> 6, lane = tid & 63;
    int wr = (wave >> 1) & 1, wc = wave & 1;
    int quad = lane >> 4, l16 = lane & 15;

    const ushort_t* ayp = y1 + (long long)mt0 * 16 * 512 + lane * 8;
    const ushort_t* ahp = hid + (long long)mt0 * 16 * 512 + lane * 8;

    long long cb = (long long)blockIdx.y * 16 * 2048 + lane * 8;
    const ushort_t* wbg[6];
    #pragma unroll
    for (int g = 0; g < 3; g++) wbg[g] = wihp + (long long)g * 262144 + cb;
    #pragma unroll
    for (int g = 3; g < 6; g++) wbg[g] = whhp + (long long)(g - 3) * 262144 + cb;

    f32x4 acc[4][2][2];
    #pragma unroll
    for (int g = 0; g < 4; g++)
        #pragma unroll
        for (int i = 0; i < 2; i++)
            #pragma unroll
            for (int j = 0; j < 2; j++) acc[g][i][j] = (f32x4){0.f, 0.f, 0.f, 0.f};

    bf16x8 ayA[2], ahA[2], bbA[6][2];
    bf16x8 ayB[2], ahB[2], bbB[6][2];

#define RLOADS(AY, AH, BB, kkv) do {                                          \
    _Pragma("unroll") for (int i2 = 0; i2 < 2; i2++) {                        \
        AY[i2] = *(const bf16x8*)(ayp + ((long long)(wr * 2 + i2) * 16 + (kkv)) * 512); \
        AH[i2] = *(const bf16x8*)(ahp + ((long long)(wr * 2 + i2) * 16 + (kkv)) * 512); } \
    _Pragma("unroll") for (int g2 = 0; g2 < 6; g2++)                          \
        _Pragma("unroll") for (int u2 = 0; u2 < 2; u2++)                      \
            BB[g2][u2] = *(const bf16x8*)(wbg[g2] + ((kkv) * 4 + wc * 2 + u2) * 512); \
} while (0)
#define RMFMAS(AY, AH, BB) do {                                               \
    _Pragma("unroll") for (int g2 = 0; g2 < 3; g2++) {                        \
        int ai = (g2 < 2) ? g2 : 2;                                           \
        int ah2 = (g2 < 2) ? g2 : 3;                                          \
        _Pragma("unroll") for (int i2 = 0; i2 < 2; i2++)                      \
            _Pragma("unroll") for (int j2 = 0; j2 < 2; j2++) {                \
                acc[ai][i2][j2] = __builtin_amdgcn_mfma_f32_16x16x32_bf16(    \
                    AY[i2], BB[g2][j2], acc[ai][i2][j2], 0, 0, 0);            \
                acc[ah2][i2][j2] = __builtin_amdgcn_mfma_f32_16x16x32_bf16(   \
                    AH[i2], BB[g2 + 3][j2], acc[ah2][i2][j2], 0, 0, 0); } }   \
} while (0)

    RLOADS(ayA, ahA, bbA, 0);
    #pragma unroll 1
    for (int kk2 = 0; kk2 < 8; kk2++) {
        RLOADS(ayB, ahB, bbB, kk2 * 2 + 1);
        RMFMAS(ayA, ahA, bbA);
        if (kk2 < 7) RLOADS(ayA, ahA, bbA, kk2 * 2 + 2);
        RMFMAS(ayB, ahB, bbB);
    }
#undef RLOADS
#undef RMFMAS

    __shared__ ushort_t Cs[64 * 72];
    int c0 = blockIdx.y * 64;
    #pragma unroll
    for (int i = 0; i < 2; i++) {
        #pragma unroll
        for (int r = 0; r < 4; r++) {
            int rowL = wr * 32 + i * 16 + quad * 4 + r;
            int pos = pos0 + rowL;
            int norig = perm[pos];
            bool realr = norig < 8192;
            int nr = realr ? norig : 0;
            #pragma unroll
            for (int j = 0; j < 2; j++) {
                int colL = wc * 32 + j * 16 + l16;
                int col = c0 + colL;
                float sr = acc[0][i][j][r] + bih[col] + bhh[col];
                float sz = acc[1][i][j][r] + bih[H + col] + bhh[H + col];
                float in_ = acc[2][i][j][r] + bih[2 * H + col];
                float hn = acc[3][i][j][r] + bhh[2 * H + col];
                float rg = sigmoidf_(sr);
                float zg = sigmoidf_(sz);
                float ng = tanhf(in_ + rg * hn);
                float hv = hidden_f[(long long)nr * H + col];
                float hnew = (1.f - zg) * ng + zg * hv;
                if (realr) out_h_f[(long long)norig * H + col] = hnew;
                Cs[rowL * 72 + colL] = f2b(hnew);
            }
        }
    }
    __syncthreads();
    // packed-A store of hp: 4 mt x 2 kkL x 64 lanes = 512 slots, 2/thread
    #pragma unroll
    for (int s2 = 0; s2 < 2; s2++) {
        int slot = s2 * 256 + tid;
        int l = slot & 63, t4 = slot >> 6;
        int mt = t4 >> 1, kkL = t4 & 1;
        us8 v = *(const us8*)(&Cs[(mt * 16 + (l & 15)) * 72 + kkL * 32 + (l >> 4) * 8]);
        *(us8*)(hp + ((long long)(mt0 + mt) * 16 + blockIdx.y * 2 + kkL) * 512 + l * 8) = v;
    }
}

// ---------------------------------------------------------------------------
extern "C" void kernel_launch(void* const* d_in, const int* in_sizes, int n_in,
                              void* d_out, int out_size, void* d_ws, size_t ws_size,
                              hipStream_t stream) {
    (void)in_sizes; (void)n_in;
    const int N = 8192, A = 8, E = 64, H = 512, NA = 16;

    float* out_f = (float*)d_out;
    float* out_q = out_f;                        // [N, NA] fp32
    float* out_h = out_f + (size_t)N * NA;       // [N, H] fp32, original order

    char* p = (char*)d_ws;
    auto alloc = [&](size_t b) { char* r = p; p += (b + 255) & ~(size_t)255; return r; };
    int*  perm   = (int*)alloc((size_t)NPAD * 4);
    int*  seg    = (int*)alloc(16 * 4);
    int4* ttab   = (int4*)alloc(144 * 16);
    int*  tcount = (int*)alloc(256);
    ushort_t* wm1     = (ushort_t*)alloc((size_t)A * PACKSZ(H, E) * 2);
    ushort_t* wm2     = (ushort_t*)alloc((size_t)A * PACKSZ(H, H) * 2);
    ushort_t* wm3     = (ushort_t*)alloc((size_t)A * PACKSZ(H, H) * 2);
    ushort_t* wm4     = (ushort_t*)alloc((size_t)A * PACKSZ(NA, H) * 2);
    ushort_t* y1      = (ushort_t*)alloc((size_t)NPAD * H * 2);
    ushort_t* inp_pos = (ushort_t*)alloc((size_t)NPAD * E * 2);
    ushort_t* hid_pos = (ushort_t*)alloc((size_t)NPAD * H * 2);
    ushort_t* wihp    = (ushort_t*)alloc((size_t)3 * H * H * 2);
    ushort_t* whhp    = (ushort_t*)alloc((size_t)3 * H * H * 2);
    ushort_t* hp      = (ushort_t*)alloc((size_t)NPAD * H * 2);
    size_t need = (size_t)(p - (char*)d_ws);
    ushort_t* q2 = y1;       // alias: y1 dead after gru_fused
    ushort_t* q3 = hid_pos;  // alias: hid_pos dead after gru_fused

    if (ws_size < need) {
        fill_kernel<<<(unsigned)((out_size + 255) / 256), 256, 0, stream>>>(
            out_f, out_size, 1000.f);
        return;
    }

    const float* inputs = (const float*)d_in[0];
    const float* hidden = (const float*)d_in[1];
    const int*   ids    = (const int*)d_in[2];
    const float* fc1_w  = (const float*)d_in[3];
    const float* fc1_b  = (const float*)d_in[4];
    const float* fc1_al = (const float*)d_in[5];
    const float* wih    = (const float*)d_in[6];
    const float* whh    = (const float*)d_in[7];
    const float* bih    = (const float*)d_in[8];
    const float* bhh    = (const float*)d_in[9];
    const float* fc2_w  = (const float*)d_in[10];
    const float* fc2_b  = (const float*)d_in[11];
    const float* fc2_al = (const float*)d_in[12];
    const float* fc3_w  = (const float*)d_in[13];
    const float* fc3_b  = (const float*)d_in[14];
    const float* fc3_al = (const float*)d_in[15];
    const float* fc4_w  = (const float*)d_in[16];
    const float* fc4_b  = (const float*)d_in[17];
    const float* fc4_al = (const float*)d_in[18];

    sort_kernel<<<1, 1024, 0, stream>>>(ids, N, perm, seg, ttab, tcount);

    prep_kernel<<<PREP_BLOCKS, 256, 0, stream>>>(
        fc1_al, fc1_w, wm1, fc2_al, fc2_w, wm2, fc3_al, fc3_w, wm3,
        fc4_al, fc4_w, wm4, inputs, inp_pos, hidden, hid_pos,
        wih, wihp, whh, whhp, perm);

    dim3 blk(256);
    gemm_tiled<ushort_t, 2, 1><<<dim3(136, H / 128), blk, 0, stream>>>(
        inp_pos, E, wm1, PACKSZ(H, E), fc1_b, y1, H, ttab, tcount,
        perm, H, 1);
    gru_fused<<<dim3(136, H / 64), blk, 0, stream>>>(
        y1, hid_pos, hidden, wihp, whhp, bih, bhh, perm, out_h, hp,
        ttab, tcount, H);
    gemm_tiled<ushort_t, 2, 1><<<dim3(136, H / 128), blk, 0, stream>>>(
        hp, H, wm2, PACKSZ(H, H), fc2_b, q2, H, ttab, tcount,
        perm, H, 1);
    gemm_tiled<ushort_t, 2, 1><<<dim3(136, H / 128), blk, 0, stream>>>(
        q2, H, wm3, PACKSZ(H, H), fc3_b, q3, H, ttab, tcount,
        perm, H, 1);
    gemm_tiled<float, 1, 0><<<dim3(136, 1), blk, 0, stream>>>(
        q3, H, wm4, PACKSZ(NA, H), fc4_b, out_q, NA, ttab, tcount,
        perm, NA, 0);
}